// Round 2
// baseline (96.299 us; speedup 1.0000x reference)
//
#include <hip/hip_runtime.h>

#define NN 5000
#define TT 12
#define DAYD 8
#define FF 7
#define DIMD 96
#define MAXE 512

// ---------------------------------------------------------------------------
// Kernel 1: AGG[n][t*8+d] = (1/deg[n]) * sum_{j in nnz(adj[n])} data[t][j][d]
// One block per row n. adj row = 5000 f32 = 1250 float4 (20000 B, 16B-aligned).
// Density 0.005 -> ~25 nnz/row (P(nnz>512) ~ 0). adj values are exactly 1.0,
// so deg = count and the aggregation is a mean over neighbor columns.
// Deterministic two-phase collect (count -> prefix -> fill), no atomics.
// ---------------------------------------------------------------------------
__global__ void __launch_bounds__(256)
agg_kernel(const float* __restrict__ adj,
           const float* __restrict__ data,
           float* __restrict__ agg_out) {
    __shared__ unsigned short s_cols[MAXE];
    __shared__ int s_pref[256];
    __shared__ int s_total;

    const int n = blockIdx.x;
    const int tid = threadIdx.x;

    const float4* row = (const float4*)(adj + (size_t)n * NN);

    int mycnt = 0;
    for (int chunk = tid; chunk < 1250; chunk += 256) {
        float4 w = row[chunk];
        mycnt += (w.x != 0.f) + (w.y != 0.f) + (w.z != 0.f) + (w.w != 0.f);
    }
    s_pref[tid] = mycnt;
    __syncthreads();
    if (tid == 0) {
        int acc = 0;
        #pragma unroll 8
        for (int i = 0; i < 256; ++i) { int c = s_pref[i]; s_pref[i] = acc; acc += c; }
        s_total = acc;
    }
    __syncthreads();

    int p = s_pref[tid];
    for (int chunk = tid; chunk < 1250; chunk += 256) {
        float4 w = row[chunk];
        int base = chunk * 4;
        if (w.x != 0.f) { if (p < MAXE) s_cols[p] = (unsigned short)(base + 0); ++p; }
        if (w.y != 0.f) { if (p < MAXE) s_cols[p] = (unsigned short)(base + 1); ++p; }
        if (w.z != 0.f) { if (p < MAXE) s_cols[p] = (unsigned short)(base + 2); ++p; }
        if (w.w != 0.f) { if (p < MAXE) s_cols[p] = (unsigned short)(base + 3); ++p; }
    }
    __syncthreads();

    const int cnt = min(s_total, MAXE);
    if (tid < DIMD) {
        const int t = tid >> 3, d = tid & 7;
        float acc = 0.f;
        for (int e = 0; e < cnt; ++e) {
            int j = s_cols[e];
            acc += data[((size_t)t * NN + j) * DAYD + d];
        }
        float scale = (cnt > 0) ? (1.f / (float)cnt) : 0.f;
        agg_out[(size_t)n * DIMD + tid] = acc * scale;
    }
}

// ---------------------------------------------------------------------------
// Kernel 2: the sequential T-loop. One thread per node n. All weights in LDS.
// masks[1] == 0 (jnp.power is ELEMENTWISE; adj binary -> adj^2 == adj, so the
// L=2 mask is identically zero): his_W cols 14..20 and cur_W col 2 are skipped.
// Prefix matmuls (weight prefix never changes) become running accumulators.
// ---------------------------------------------------------------------------
__global__ void __launch_bounds__(256)
seq_kernel(const float* __restrict__ data,
           const float* __restrict__ pos,
           const float* __restrict__ hisW,   // (T, F, 28)
           const float* __restrict__ curW,   // (T, 1, 4)
           const float* __restrict__ hisw,   // (F, 95)
           const float* __restrict__ curw,   // (1, 12)
           const float* __restrict__ agg,    // (N, 96) f32 ws
           float* __restrict__ final_out) {  // (N, 96) f32 ws
    __shared__ float s_hisW[TT * FF * 28];  // 2352
    __shared__ float s_curW[TT * 4];        // 48
    __shared__ float s_hw[FF * 95];         // 665
    __shared__ float s_cw[TT];              // 12

    const int tid = threadIdx.x;
    for (int i = tid; i < TT * FF * 28; i += 256) s_hisW[i] = hisW[i];
    for (int i = tid; i < TT * 4; i += 256)       s_curW[i] = curW[i];
    for (int i = tid; i < FF * 95; i += 256)      s_hw[i]   = hisw[i];
    for (int i = tid; i < TT; i += 256)           s_cw[i]   = curw[i];
    __syncthreads();

    const int n = blockIdx.x * 256 + tid;
    if (n >= NN) return;

    float his_h[TT][FF];
    float cur_c[TT];
    float run_his[FF] = {0, 0, 0, 0, 0, 0, 0};
    float his_prev[FF] = {0, 0, 0, 0, 0, 0, 0};
    float run_cur = 0.f, cur_prev = 0.f;

    #pragma unroll
    for (int t = 0; t < TT; ++t) {
        float d[8], p[8], a[8];
        float4 d0 = *(const float4*)(data + ((size_t)t * NN + n) * DAYD);
        float4 d1 = *(const float4*)(data + ((size_t)t * NN + n) * DAYD + 4);
        float4 p0 = *(const float4*)(pos  + ((size_t)t * NN + n) * DAYD);
        float4 p1 = *(const float4*)(pos  + ((size_t)t * NN + n) * DAYD + 4);
        d[0]=d0.x; d[1]=d0.y; d[2]=d0.z; d[3]=d0.w; d[4]=d1.x; d[5]=d1.y; d[6]=d1.z; d[7]=d1.w;
        p[0]=p0.x; p[1]=p0.y; p[2]=p0.z; p[3]=p0.w; p[4]=p1.x; p[5]=p1.y; p[6]=p1.z; p[7]=p1.w;
        #pragma unroll
        for (int k = 0; k < 8; ++k) a[k] = agg[(size_t)n * DIMD + t * 8 + k];

        const float* W = s_hisW + t * FF * 28;
        float h[FF];
        #pragma unroll
        for (int o = 0; o < FF; ++o) {
            const float* wo = W + o * 28;
            float s = 0.f;
            #pragma unroll
            for (int k = 0; k < FF; ++k)
                s += d[k] * wo[k] + a[k] * wo[7 + k] + his_prev[k] * wo[21 + k];
            h[o] = fmaxf(s, 0.f) + p[o];
        }
        #pragma unroll
        for (int o = 0; o < FF; ++o) his_h[t][o] = h[o];

        // his_prev = relu(concat(h_0..h_t) @ his_weight[:, :(t+1)F].T)
        #pragma unroll
        for (int o = 0; o < FF; ++o) {
            float s = run_his[o];
            #pragma unroll
            for (int k = 0; k < FF; ++k) s += h[k] * s_hw[o * 95 + t * FF + k];
            run_his[o] = s;
            his_prev[o] = fmaxf(s, 0.f);
        }

        float c = d[7] * s_curW[t * 4 + 0] + a[7] * s_curW[t * 4 + 1]
                + cur_prev * s_curW[t * 4 + 3];
        c = fmaxf(c, 0.f) + p[7];
        cur_c[t] = c;
        run_cur += c * s_cw[t];
        cur_prev = fmaxf(run_cur, 0.f);
    }

    float* fo = final_out + (size_t)n * DIMD;
    #pragma unroll
    for (int t = 0; t < TT; ++t)
        #pragma unroll
        for (int o = 0; o < FF; ++o) fo[t * FF + o] = his_h[t][o];
    #pragma unroll
    for (int t = 0; t < TT; ++t) fo[84 + t] = cur_c[t];
}

// ---------------------------------------------------------------------------
// Kernel 3: out = relu(final @ FW^T), f32 out. One block per row n.
// ---------------------------------------------------------------------------
__global__ void __launch_bounds__(128)
final_kernel(const float* __restrict__ fin,
             const float* __restrict__ fw,
             float* __restrict__ out) {
    __shared__ float s_row[DIMD];
    const int n = blockIdx.x;
    const int tid = threadIdx.x;
    if (tid < DIMD) s_row[tid] = fin[(size_t)n * DIMD + tid];
    __syncthreads();
    if (tid < DIMD) {
        const float* wr = fw + (size_t)tid * DIMD;
        float s = 0.f;
        #pragma unroll
        for (int k = 0; k < DIMD; ++k) s += s_row[k] * wr[k];
        out[(size_t)n * DIMD + tid] = fmaxf(s, 0.f);
    }
}

extern "C" void kernel_launch(void* const* d_in, const int* in_sizes, int n_in,
                              void* d_out, int out_size, void* d_ws, size_t ws_size,
                              hipStream_t stream) {
    const float* adj  = (const float*)d_in[0];
    const float* data = (const float*)d_in[1];
    const float* pos  = (const float*)d_in[2];
    const float* hisW = (const float*)d_in[3];
    const float* curW = (const float*)d_in[4];
    const float* hisw = (const float*)d_in[5];
    const float* curw = (const float*)d_in[6];
    const float* fw   = (const float*)d_in[7];
    float* out = (float*)d_out;

    float* ws_agg   = (float*)d_ws;                   // N*96 f32
    float* ws_final = ws_agg + (size_t)NN * DIMD;     // N*96 f32

    agg_kernel<<<NN, 256, 0, stream>>>(adj, data, ws_agg);
    seq_kernel<<<(NN + 255) / 256, 256, 0, stream>>>(data, pos, hisW, curW,
                                                     hisw, curw, ws_agg, ws_final);
    final_kernel<<<NN, 128, 0, stream>>>(ws_final, fw, out);
}